// Round 1
// 342.469 us; speedup vs baseline: 1.0231x; 1.0231x over previous
//
#include <hip/hip_runtime.h>

#define N_NODES 50000
#define N_EDGES 800000
#define D 128
#define PLANE ((size_t)N_NODES * D)
#define NCHUNK ((N_NODES + 255) / 256)  // 196

typedef float f32x4 __attribute__((ext_vector_type(4)));
typedef float f32x2 __attribute__((ext_vector_type(2)));
typedef short bf16x8 __attribute__((ext_vector_type(8)));

__device__ __forceinline__ unsigned short f2bf(float x) {
  unsigned int u = __float_as_uint(x);
  u += 0x7FFFu + ((u >> 16) & 1u);  // RNE
  return (unsigned short)(u >> 16);
}
// HW OCP e4m3 convert (gfx950)
__device__ __forceinline__ unsigned char f32_to_fp8(float x) {
  int p = __builtin_amdgcn_cvt_pk_fp8_f32(x, x, 0, false);
  return (unsigned char)(p & 0xFF);
}

// ---------------- CSR build + degree-bucket sort ----------------
// Degree histogram / scan / scatter are fused into the existing three
// scan kernels via LDS histograms (no extra dispatches, no hot global atomics).

__global__ __launch_bounds__(256) void scan_local(const int* __restrict__ cnt,
                                                  int* __restrict__ local,
                                                  int* __restrict__ partial,
                                                  int* __restrict__ bcnt) {
  __shared__ int s[256];
  __shared__ int hist[64];
  int t = threadIdx.x;
  if (t < 64) hist[t] = 0;
  int i = blockIdx.x * 256 + t;
  int v = (i < N_NODES) ? cnt[i] : 0;
  s[t] = v;
  __syncthreads();
  if (i < N_NODES) atomicAdd(&hist[v < 63 ? v : 63], 1);
  for (int off = 1; off < 256; off <<= 1) {
    int tmp = (t >= off) ? s[t - off] : 0;
    __syncthreads();
    s[t] += tmp;
    __syncthreads();
  }
  if (i < N_NODES) local[i] = s[t] - v;
  if (t == 255) partial[blockIdx.x] = s[255];
  if (t < 64) atomicAdd(&bcnt[t], hist[t]);  // block-aggregated: 196 atomics/bucket
}

__global__ __launch_bounds__(256) void scan_chunks(const int* __restrict__ partial,
                                                   int* __restrict__ chunk_off,
                                                   int* __restrict__ rowptr,
                                                   const int* __restrict__ bcnt,
                                                   int* __restrict__ gcur) {
  __shared__ int s[256];
  __shared__ int sb[64];
  __shared__ int sbb[64];
  int t = threadIdx.x;
  int v = (t < NCHUNK) ? partial[t] : 0;
  s[t] = v;
  if (t < 64) sb[t] = bcnt[t];
  __syncthreads();
  if (t == 0) {  // serial 64-wide exclusive scan of degree buckets (LDS, cheap)
    int run = 0;
    for (int q = 0; q < 64; ++q) { sbb[q] = run; run += sb[q]; }
  }
  for (int off = 1; off < 256; off <<= 1) {
    int tmp = (t >= off) ? s[t - off] : 0;
    __syncthreads();
    s[t] += tmp;
    __syncthreads();
  }
  if (t < NCHUNK) chunk_off[t] = s[t] - v;
  if (t == 255) rowptr[N_NODES] = s[255];
  if (t < 64) gcur[t] = sbb[t];  // bucket cursors start at bucket bases
}

__global__ __launch_bounds__(256) void finalize_rows(const int* __restrict__ cnt,
                                                     const int* __restrict__ local,
                                                     const int* __restrict__ chunk_off,
                                                     int* __restrict__ rowptr,
                                                     int* __restrict__ cursor,
                                                     float* __restrict__ norm,
                                                     int* __restrict__ gcur,
                                                     int* __restrict__ perm) {
  __shared__ int hcnt[64];
  __shared__ int hbase[64];
  int t = threadIdx.x;
  if (t < 64) hcnt[t] = 0;
  __syncthreads();
  int i = blockIdx.x * 256 + t;
  int b = 0;
  if (i < N_NODES) {
    int r = local[i] + chunk_off[blockIdx.x];
    rowptr[i] = r;
    cursor[i] = r;
    int d = cnt[i];
    b = d < 63 ? d : 63;
    atomicAdd(&hcnt[b], 1);
    if (d < 1) d = 1;
    norm[i] = rsqrtf((float)d);
  }
  __syncthreads();
  if (t < 64) {
    hbase[t] = atomicAdd(&gcur[t], hcnt[t]);  // claim a contiguous range per block
    hcnt[t] = 0;
  }
  __syncthreads();
  if (i < N_NODES) {
    int lp = atomicAdd(&hcnt[b], 1);  // local rank (LDS atomic, low contention)
    perm[hbase[b] + lp] = i;
  }
}

// ---------------- prep: feats->bf16 + weight transposes + deg count ----------------

#define CONV_THREADS ((int)(PLANE / 4))            // 1,600,000
#define WT_THREADS (2 * 3 * 128 * 256)             // 196,608
#define PREP_TOTAL (CONV_THREADS + WT_THREADS + N_EDGES)

__global__ __launch_bounds__(256) void prep_all(const float* __restrict__ feats,
                                                const float* __restrict__ w0,
                                                const float* __restrict__ w,
                                                const float* __restrict__ v,
                                                const int* __restrict__ dst,
                                                unsigned short* __restrict__ feats_bf,
                                                unsigned short* __restrict__ bt_h1,
                                                unsigned short* __restrict__ bt_out,
                                                int* __restrict__ cnt) {
  int idx = blockIdx.x * 256 + threadIdx.x;
  if (idx < CONV_THREADS) {
    float4 x = ((const float4*)feats)[idx];
    ushort4 o;
    o.x = f2bf(x.x);
    o.y = f2bf(x.y);
    o.z = f2bf(x.z);
    o.w = f2bf(x.w);
    ((ushort4*)feats_bf)[idx] = o;
    return;
  }
  idx -= CONV_THREADS;
  if (idx < WT_THREADS) {
    int buf = idx / 98304;
    int rem = idx - buf * 98304;
    int stack = rem / 32768;
    int rem2 = rem & 32767;
    int n = rem2 >> 8;
    int k = rem2 & 255;
    const float* srcm;
    int kk;
    if (k < 128) {
      srcm = (buf == 0) ? w0 : w;
      kk = k;
    } else {
      srcm = v;
      kk = k - 128;
    }
    float val = srcm[(size_t)stack * 16384 + (size_t)kk * 128 + n];
    unsigned short* dstb = (buf == 0) ? bt_h1 : bt_out;
    dstb[(size_t)stack * 32768 + (size_t)n * 256 + k] = f2bf(val);
    return;
  }
  idx -= WT_THREADS;
  if (idx < N_EDGES) atomicAdd(&cnt[dst[idx]], 1);
}

// fill CSR + feats_fp8 = fp8(norm * feats)  (norm folded into the src operand)
__global__ __launch_bounds__(256) void csr_fp8(const int* __restrict__ src,
                                               const int* __restrict__ dst,
                                               int* __restrict__ cursor,
                                               int* __restrict__ col,
                                               const float* __restrict__ feats,
                                               const float* __restrict__ norm,
                                               unsigned char* __restrict__ feats_fp8) {
  int idx = blockIdx.x * 256 + threadIdx.x;
  if (idx < CONV_THREADS) {
    float4 x = ((const float4*)feats)[idx];
    float nv = norm[idx >> 5];  // 32 float4 per 128-feat row
    int p = __builtin_amdgcn_cvt_pk_fp8_f32(x.x * nv, x.y * nv, 0, false);
    p = __builtin_amdgcn_cvt_pk_fp8_f32(x.z * nv, x.w * nv, p, true);
    ((int*)feats_fp8)[idx] = p;
    return;
  }
  idx -= CONV_THREADS;
  if (idx < N_EDGES) {
    int pos = atomicAdd(&cursor[dst[idx]], 1);
    col[pos] = src[idx];
  }
}

// ---------------- SpMM: 8 lanes per row, serial edges, no cross-lane reduce ----------
// Wave = 8 degree-sorted rows (perm). Lane l of a group owns feats [l*16, l*16+16).
// Source planes are pre-scaled by norm[src]; per edge: 1 col load + NK contiguous
// int4 gathers + packed-f32 adds. Dst norm applied once in the epilogue.

template <int NK, int STRIDE>
__global__ __launch_bounds__(256) void spmm_rows(const unsigned char* __restrict__ h,
                                                 const float* __restrict__ norm,
                                                 const int* __restrict__ rowptr,
                                                 const int* __restrict__ col,
                                                 const int* __restrict__ perm,
                                                 unsigned short* __restrict__ out) {
  int gi = blockIdx.x * 32 + (threadIdx.x >> 3);
  if (gi >= N_NODES) return;
  int l = threadIdx.x & 7;
  int row = perm[gi];
  int beg = rowptr[row], end = rowptr[row + 1];

  f32x2 acc[NK][8];
#pragma unroll
  for (int m = 0; m < NK; ++m)
#pragma unroll
    for (int j = 0; j < 8; ++j) acc[m][j] = (f32x2)(0.f);

#pragma unroll 2
  for (int e = beg; e < end; ++e) {
    int s = col[e];
    const unsigned char* hp = h + (size_t)s * STRIDE + l * 16;
#pragma unroll
    for (int m = 0; m < NK; ++m) {
      int4 p = *(const int4*)(hp + m * 128);
      acc[m][0] += __builtin_amdgcn_cvt_pk_f32_fp8(p.x, false);
      acc[m][1] += __builtin_amdgcn_cvt_pk_f32_fp8(p.x, true);
      acc[m][2] += __builtin_amdgcn_cvt_pk_f32_fp8(p.y, false);
      acc[m][3] += __builtin_amdgcn_cvt_pk_f32_fp8(p.y, true);
      acc[m][4] += __builtin_amdgcn_cvt_pk_f32_fp8(p.z, false);
      acc[m][5] += __builtin_amdgcn_cvt_pk_f32_fp8(p.z, true);
      acc[m][6] += __builtin_amdgcn_cvt_pk_f32_fp8(p.w, false);
      acc[m][7] += __builtin_amdgcn_cvt_pk_f32_fp8(p.w, true);
    }
  }

  float nd = norm[row];
#pragma unroll
  for (int m = 0; m < NK; ++m) {
    bf16x8 o0, o1;
#pragma unroll
    for (int j = 0; j < 4; ++j) {
      o0[2 * j] = (short)f2bf(acc[m][j].x * nd);
      o0[2 * j + 1] = (short)f2bf(acc[m][j].y * nd);
      o1[2 * j] = (short)f2bf(acc[m][j + 4].x * nd);
      o1[2 * j + 1] = (short)f2bf(acc[m][j + 4].y * nd);
    }
    unsigned short* op = out + (size_t)m * PLANE + (size_t)row * D + l * 16;
    *(bf16x8*)op = o0;
    *(bf16x8*)(op + 8) = o1;
  }
}

// ---------------- MFMA GEMM ----------------
// Block: 256 threads = 4 waves, M-tile 128 rows, N-tile 64 cols (blockIdx.y).
// B half-tile (64n x 256k bf16 = 32 KB) in LDS, XOR-swizzled (2-way max).
// Stacks looped in-kernel; shared-A fragments hoisted into registers.

__device__ __forceinline__ void stage_B64(unsigned short (*Bs)[256],
                                          const unsigned short* __restrict__ Btg,
                                          int nh, int tid) {
#pragma unroll
  for (int i = 0; i < 8; ++i) {
    int t = tid + i * 256;       // 0..2047 16B-chunks
    int n = t >> 5;              // 0..63
    int kc = t & 31;
    int kcs = kc ^ (n & 31);     // swizzle
    *(bf16x8*)&Bs[n][kcs * 8] = *(const bf16x8*)(Btg + (size_t)(nh + n) * 256 + kc * 8);
  }
}

__device__ __forceinline__ bf16x8 read_B64(const unsigned short (*Bs)[256], int n,
                                           int chunk) {
  return *(const bf16x8*)&Bs[n][(chunk ^ (n & 31)) * 8];
}

// layer-1: h1[node][stk][128] = fp8( norm[node] * relu(P @ w0[stk] + feats @ v[stk] + b) )
// Interleaved output layout -> spmm<3> gathers one contiguous 384 B burst per edge.
__global__ __launch_bounds__(256) void gemm_h1_fused(
    const unsigned short* __restrict__ P,
    const unsigned short* __restrict__ feats_bf,
    const unsigned short* __restrict__ Bt,
    const float* __restrict__ b0, const float* __restrict__ bv,
    const float* __restrict__ norm,
    unsigned char* __restrict__ h1_fp8) {
  __shared__ unsigned short Bs[64][256];
  int nh = blockIdx.y * 64;

  int tid = threadIdx.x;
  int lane = tid & 63;
  int wv = tid >> 6;
  int ln15 = lane & 15;
  int g = lane >> 4;

  int m0 = blockIdx.x * 128 + wv * 32;
  int r0 = m0 + ln15;
  int r1 = m0 + 16 + ln15;
  if (r0 >= N_NODES) r0 = N_NODES - 1;
  if (r1 >= N_NODES) r1 = N_NODES - 1;

  bf16x8 a0[8], a1[8];  // s=0..3 from P (k<128), s=4..7 from feats (k>=128)
#pragma unroll
  for (int s = 0; s < 4; ++s) {
    a0[s] = *(const bf16x8*)(P + (size_t)r0 * 128 + g * 8 + s * 32);
    a1[s] = *(const bf16x8*)(P + (size_t)r1 * 128 + g * 8 + s * 32);
    a0[s + 4] = *(const bf16x8*)(feats_bf + (size_t)r0 * 128 + g * 8 + s * 32);
    a1[s + 4] = *(const bf16x8*)(feats_bf + (size_t)r1 * 128 + g * 8 + s * 32);
  }

  float nA[4], nB[4];
#pragma unroll
  for (int r = 0; r < 4; ++r) {
    int mA = m0 + g * 4 + r;
    int mB = m0 + 16 + g * 4 + r;
    nA[r] = (mA < N_NODES) ? norm[mA] : 0.f;
    nB[r] = (mB < N_NODES) ? norm[mB] : 0.f;
  }

  for (int stk = 0; stk < 3; ++stk) {
    if (stk) __syncthreads();
    stage_B64(Bs, Bt + (size_t)stk * 32768, nh, tid);
    __syncthreads();

    f32x4 acc0[4], acc1[4];
#pragma unroll
    for (int nt = 0; nt < 4; ++nt) { acc0[nt] = (f32x4)(0.f); acc1[nt] = (f32x4)(0.f); }

#pragma unroll
    for (int s = 0; s < 8; ++s) {
#pragma unroll
      for (int nt = 0; nt < 4; ++nt) {
        bf16x8 bfr = read_B64(Bs, nt * 16 + ln15, s * 4 + g);
        acc0[nt] = __builtin_amdgcn_mfma_f32_16x16x32_bf16(a0[s], bfr, acc0[nt], 0, 0, 0);
        acc1[nt] = __builtin_amdgcn_mfma_f32_16x16x32_bf16(a1[s], bfr, acc1[nt], 0, 0, 0);
      }
    }

#pragma unroll
    for (int nt = 0; nt < 4; ++nt) {
      int colj = nh + nt * 16 + ln15;
      float bsum = b0[stk * 128 + colj] + bv[stk * 128 + colj];
#pragma unroll
      for (int r = 0; r < 4; ++r) {
        int mA = m0 + g * 4 + r;
        int mB = m0 + 16 + g * 4 + r;
        if (mA < N_NODES) {
          float x = acc0[nt][r] + bsum;
          x = x > 0.f ? x : 0.f;
          h1_fp8[(size_t)mA * 384 + stk * 128 + colj] = f32_to_fp8(x * nA[r]);
        }
        if (mB < N_NODES) {
          float x = acc1[nt][r] + bsum;
          x = x > 0.f ? x : 0.f;
          h1_fp8[(size_t)mB * 384 + stk * 128 + colj] = f32_to_fp8(x * nB[r]);
        }
      }
    }
  }
}

// layer-2 fused: out = (1/3) * sum_stk relu(agg[stk] @ w[stk] + feats @ v[stk] + bw + bv)
__global__ __launch_bounds__(256) void gemm_out_fused(
    const unsigned short* __restrict__ agg,
    const unsigned short* __restrict__ feats_bf,
    const unsigned short* __restrict__ Bt,
    const float* __restrict__ bwp, const float* __restrict__ bvp,
    float* __restrict__ outp) {
  __shared__ unsigned short Bs[64][256];
  int nh = blockIdx.y * 64;

  int tid = threadIdx.x;
  int lane = tid & 63;
  int wv = tid >> 6;
  int ln15 = lane & 15;
  int g = lane >> 4;

  int m0 = blockIdx.x * 128 + wv * 32;
  int r0 = m0 + ln15;
  int r1 = m0 + 16 + ln15;
  if (r0 >= N_NODES) r0 = N_NODES - 1;
  if (r1 >= N_NODES) r1 = N_NODES - 1;

  bf16x8 f0[4], f1[4];  // feats frags (k=128..255 phase)
#pragma unroll
  for (int s = 0; s < 4; ++s) {
    f0[s] = *(const bf16x8*)(feats_bf + (size_t)r0 * 128 + g * 8 + s * 32);
    f1[s] = *(const bf16x8*)(feats_bf + (size_t)r1 * 128 + g * 8 + s * 32);
  }

  f32x4 sum0[4], sum1[4];
#pragma unroll
  for (int nt = 0; nt < 4; ++nt) { sum0[nt] = (f32x4)(0.f); sum1[nt] = (f32x4)(0.f); }

  for (int stk = 0; stk < 3; ++stk) {
    if (stk) __syncthreads();
    stage_B64(Bs, Bt + (size_t)stk * 32768, nh, tid);
    __syncthreads();

    const unsigned short* A1 = agg + (size_t)stk * PLANE;
    bf16x8 g0[4], g1[4];
#pragma unroll
    for (int s = 0; s < 4; ++s) {
      g0[s] = *(const bf16x8*)(A1 + (size_t)r0 * 128 + g * 8 + s * 32);
      g1[s] = *(const bf16x8*)(A1 + (size_t)r1 * 128 + g * 8 + s * 32);
    }

    f32x4 acc0[4], acc1[4];
#pragma unroll
    for (int nt = 0; nt < 4; ++nt) { acc0[nt] = (f32x4)(0.f); acc1[nt] = (f32x4)(0.f); }

#pragma unroll
    for (int s = 0; s < 8; ++s) {
      bf16x8 af0 = (s < 4) ? g0[s & 3] : f0[s & 3];
      bf16x8 af1 = (s < 4) ? g1[s & 3] : f1[s & 3];
#pragma unroll
      for (int nt = 0; nt < 4; ++nt) {
        bf16x8 bfr = read_B64(Bs, nt * 16 + ln15, s * 4 + g);
        acc0[nt] = __builtin_amdgcn_mfma_f32_16x16x32_bf16(af0, bfr, acc0[nt], 0, 0, 0);
        acc1[nt] = __builtin_amdgcn_mfma_f32_16x16x32_bf16(af1, bfr, acc1[nt], 0, 0, 0);
      }
    }

#pragma unroll
    for (int nt = 0; nt < 4; ++nt) {
      int colj = nh + nt * 16 + ln15;
      float bsum = bwp[stk * 128 + colj] + bvp[stk * 128 + colj];
#pragma unroll
      for (int r = 0; r < 4; ++r) {
        float x0 = acc0[nt][r] + bsum;
        float x1 = acc1[nt][r] + bsum;
        sum0[nt][r] += (x0 > 0.f ? x0 : 0.f);
        sum1[nt][r] += (x1 > 0.f ? x1 : 0.f);
      }
    }
  }

  const float sc = 1.0f / 3.0f;
#pragma unroll
  for (int nt = 0; nt < 4; ++nt) {
    int colj = nh + nt * 16 + ln15;
#pragma unroll
    for (int r = 0; r < 4; ++r) {
      int mA = m0 + g * 4 + r;
      int mB = m0 + 16 + g * 4 + r;
      if (mA < N_NODES) outp[(size_t)mA * 128 + colj] = sum0[nt][r] * sc;
      if (mB < N_NODES) outp[(size_t)mB * 128 + colj] = sum1[nt][r] * sc;
    }
  }
}

// ---------------- launcher ----------------

extern "C" void kernel_launch(void* const* d_in, const int* in_sizes, int n_in,
                              void* d_out, int out_size, void* d_ws, size_t ws_size,
                              hipStream_t stream) {
  const float* feats = (const float*)d_in[0];
  const int* src = (const int*)d_in[1];
  const int* dst = (const int*)d_in[2];
  const float* w0 = (const float*)d_in[3];
  const float* b0 = (const float*)d_in[4];
  const float* w = (const float*)d_in[5];
  const float* bw = (const float*)d_in[6];
  const float* v = (const float*)d_in[7];
  const float* bv = (const float*)d_in[8];
  float* out = (float*)d_out;

  char* ws = (char*)d_ws;
  size_t off = 0;
  auto alloc = [&](size_t bytes) {
    void* p = ws + off;
    off += (bytes + 255) & ~(size_t)255;
    return p;
  };
  // cnt + bucket counters contiguous so one memset clears all
  int* cnt = (int*)alloc((N_NODES + 128) * 4);
  int* bcnt = cnt + N_NODES;
  int* gcur = bcnt + 64;
  int* local = (int*)alloc(N_NODES * 4);
  int* partial = (int*)alloc(NCHUNK * 4);
  int* chunk_off = (int*)alloc(NCHUNK * 4);
  float* norm = (float*)alloc(N_NODES * 4);
  int* rowptr = (int*)alloc((N_NODES + 1) * 4);
  int* cursor = (int*)alloc(N_NODES * 4);
  int* col = (int*)alloc(N_EDGES * 4);
  int* perm = (int*)alloc(N_NODES * 4);
  unsigned short* bt_h1 = (unsigned short*)alloc(3 * 32768 * 2);
  unsigned short* bt_out = (unsigned short*)alloc(3 * 32768 * 2);

  size_t pb = PLANE * 2;  // bf16 plane bytes
  unsigned short* feats_bf = (unsigned short*)alloc(pb);
  unsigned char* feats_fp8 = (unsigned char*)alloc(PLANE);
  unsigned short* P_bf = (unsigned short*)alloc(pb);
  unsigned char* h1_fp8 = (unsigned char*)alloc(3 * PLANE);  // interleaved [node][3][128]
  unsigned short* agg_bf = (unsigned short*)alloc(3 * pb);

  hipMemsetAsync(cnt, 0, (N_NODES + 128) * 4, stream);

  dim3 blk(256);
  // prep: feats->bf16, weight transposes, degree count (fused)
  prep_all<<<(PREP_TOTAL + 255) / 256, blk, 0, stream>>>(feats, w0, w, v, dst, feats_bf,
                                                         bt_h1, bt_out, cnt);
  scan_local<<<NCHUNK, blk, 0, stream>>>(cnt, local, partial, bcnt);
  scan_chunks<<<1, blk, 0, stream>>>(partial, chunk_off, rowptr, bcnt, gcur);
  finalize_rows<<<NCHUNK, blk, 0, stream>>>(cnt, local, chunk_off, rowptr, cursor, norm,
                                            gcur, perm);
  // CSR fill + feats_fp8 = fp8(norm * feats)
  csr_fp8<<<(CONV_THREADS + N_EDGES + 255) / 256, blk, 0, stream>>>(
      src, dst, cursor, col, feats, norm, feats_fp8);

  int sblocks = (N_NODES + 31) / 32;  // 32 rows per block (8 lanes/row)
  int mblocks = (N_NODES + 127) / 128;
  dim3 ggrid(mblocks, 2);  // x: M-tile, y: N-half (stacks looped in-kernel)

  // P = propagate(feats)   (src-norm pre-folded; dst-norm in epilogue)
  spmm_rows<1, 128><<<sblocks, blk, 0, stream>>>(feats_fp8, norm, rowptr, col, perm, P_bf);
  // h1[node][k][:] = fp8(norm * relu(P @ w0[k] + feats @ v[k] + b0[k] + bv[k]))
  gemm_h1_fused<<<ggrid, blk, 0, stream>>>(P_bf, feats_bf, bt_h1, b0, bv, norm, h1_fp8);
  // agg[k] = propagate(h1[k])  (interleaved gather: 384 B/edge contiguous)
  spmm_rows<3, 384><<<sblocks, blk, 0, stream>>>(h1_fp8, norm, rowptr, col, perm, agg_bf);
  // out = (1/3) * sum_k relu(agg[k] @ w[k] + feats @ v[k] + bw[k] + bv[k])
  gemm_out_fused<<<ggrid, blk, 0, stream>>>(agg_bf, feats_bf, bt_out, bw, bv, out);
}